// Round 17
// baseline (141.036 us; speedup 1.0000x reference)
//
#include <hip/hip_runtime.h>
#include <hip/hip_bf16.h>
#include <cstdint>
#include <cstddef>

// Problem constants (B=4, N=256, D=32, H=512)
#define NB 4
#define NN 256
#define DD 32
#define HH 512

typedef __attribute__((ext_vector_type(8))) short short8;    // 8 bf16 (4 VGPRs) — MFMA A/B frag
typedef __attribute__((ext_vector_type(4))) float f32x4;     // 16x16 C/D frag
typedef __attribute__((ext_vector_type(16))) float f32x16;   // 32x32 C/D frag

// HW packed fp32->bf16 (RNE). a -> low 16, b -> high 16.
static __device__ __forceinline__ unsigned cvtpk(float a, float b) {
  unsigned r;
  asm("v_cvt_pk_bf16_f32 %0, %1, %2" : "=v"(r) : "v"(a), "v"(b));
  return r;
}
static __device__ __forceinline__ unsigned short f2bf1(float a) {
  return (unsigned short)(cvtpk(a, 0.f) & 0xffffu);
}

// build a bf16 A/B frag from 8 consecutive fp32 (two float4 loads already done)
static __device__ __forceinline__ short8 pack8(float4 a0, float4 a1) {
  union { unsigned u[4]; short8 s; } r;
  r.u[0] = cvtpk(a0.x, a0.y); r.u[1] = cvtpk(a0.z, a0.w);
  r.u[2] = cvtpk(a1.x, a1.y); r.u[3] = cvtpk(a1.z, a1.w);
  return r.s;
}

// ---------------------------------------------------------------------------
// prep (grid 833x256):
//  blk < 512 : T-GEMM block; Tall stores predicated on motif[bi]!=0 (rows for
//              masked i are never read by fused -> skip ~half the 32 MB write).
//  blk < 576 : W2F builder (UNCHANGED).
//  blk ==576 : j-compaction + static work-queue build.
//  blk >= 577: FILL — map=0.5 / logit=0 for every (bi,j) with motif[bi]==0
//     or motif[b,j]==0 (disjoint from queue items' writes; exact constants).
// ---------------------------------------------------------------------------
__global__ __launch_bounds__(256) void prep(const float* __restrict__ z,
                                            const float* __restrict__ W1,
                                            const float* __restrict__ W2,
                                            const float* __restrict__ motif,
                                            unsigned short* __restrict__ W2F,
                                            unsigned short* __restrict__ Tall,
                                            int* __restrict__ jlist,
                                            int* __restrict__ jcnt,
                                            int* __restrict__ wq,
                                            int* __restrict__ wqn,
                                            float* __restrict__ out) {
  const int blk = blockIdx.x;
  const int tid = threadIdx.x;
  if (blk < 512) {
    __shared__ unsigned short w1s[16384];   // 32 KB: [w2][nt][lane][e]
    const int nblk = blk >> 4, mgrp = blk & 15;
    const int bibase = mgrp * 64;

    #pragma unroll
    for (int r = 0; r < 16; ++r) {
      int task = r * 256 + tid;
      int row = task >> 2;                  // dd = a*32 + c   (0..1023)
      int hq = task & 3;                    // which 4-float group of the 16 h
      float4 v = *(const float4*)(W1 + (size_t)row * 512 + nblk * 16 + hq * 4);
      int a = row >> 5, c = row & 31;
      int quad = a >> 3, e = a & 7;
      float hv[4] = {v.x, v.y, v.z, v.w};
      #pragma unroll
      for (int vv = 0; vv < 4; ++vv) {
        int hl = hq * 4 + vv;
        int nl = hl * 32 + c;               // n_local in [0,512)
        int w2 = nl >> 7, r7 = nl & 127;
        int l16 = r7 >> 3, nt = r7 & 7;
        w1s[((w2 * 8 + nt) * 64 + quad * 16 + l16) * 8 + e] = f2bf1(hv[vv]);
      }
    }
    __syncthreads();

    const int w2 = tid >> 6, lane = tid & 63;
    const int quad = lane >> 4, l16 = lane & 15;

    short8 bfr[8];
    #pragma unroll
    for (int nt = 0; nt < 8; ++nt)
      bfr[nt] = *(const short8*)&w1s[((w2 * 8 + nt) * 64 + lane) * 8];

    const int ncol = nblk * 512 + w2 * 128 + l16 * 8;
    #pragma unroll
    for (int mtg = 0; mtg < 2; ++mtg) {
      short8 afr[2];
      #pragma unroll
      for (int mi = 0; mi < 2; ++mi) {
        const float* zr = z + (size_t)(bibase + (mtg * 2 + mi) * 16 + l16) * 32 + quad * 8;
        float4 a0 = *(const float4*)(zr);
        float4 a1 = *(const float4*)(zr + 4);
        afr[mi] = pack8(a0, a1);
      }
      f32x4 d[2][8];
      #pragma unroll
      for (int mi = 0; mi < 2; ++mi)
        #pragma unroll
        for (int nt = 0; nt < 8; ++nt)
          d[mi][nt] = __builtin_amdgcn_mfma_f32_16x16x32_bf16(
              afr[mi], bfr[nt], (f32x4){0.f, 0.f, 0.f, 0.f}, 0, 0, 0);
      #pragma unroll
      for (int mi = 0; mi < 2; ++mi)
        #pragma unroll
        for (int r = 0; r < 4; ++r) {
          int rowbi = bibase + (mtg * 2 + mi) * 16 + quad * 4 + r;
          if (motif[rowbi] != 0.f) {        // masked rows never read by fused
            uint4 p;
            p.x = cvtpk(d[mi][0][r], d[mi][1][r]);
            p.y = cvtpk(d[mi][2][r], d[mi][3][r]);
            p.z = cvtpk(d[mi][4][r], d[mi][5][r]);
            p.w = cvtpk(d[mi][6][r], d[mi][7][r]);
            *(uint4*)&Tall[(size_t)rowbi * 16384 + ncol] = p;
          }
        }
    }
  } else if (blk < 576) {
    int f8 = (blk - 512) * 256 + tid;       // frag-slot index (8 elems each)
    int lane = f8 & 63;
    int nt = (f8 >> 6) & 1, s = (f8 >> 7) & 3, hc = (f8 >> 9) & 7, w = (f8 >> 12) & 3;
    int k2 = w * 64 + nt * 32 + (lane & 31);
    int hb = hc * 64 + s * 16 + (lane >> 5) * 8;
    float v[8];
    #pragma unroll
    for (int e = 0; e < 8; ++e) v[e] = W2[(hb + e) * 256 + k2];
    uint4 p;
    p.x = cvtpk(v[0], v[1]); p.y = cvtpk(v[2], v[3]);
    p.z = cvtpk(v[4], v[5]); p.w = cvtpk(v[6], v[7]);
    ((uint4*)W2F)[f8] = p;
  } else if (blk == 576) {
    // ---- compaction + queue build: wave w handles batch b = w
    __shared__ int itemc[4];
    __shared__ int baseh[4];
    const int w = tid >> 6, lane = tid & 63;
    int cnt = 0;
    if (w < NB) {
      #pragma unroll
      for (int ch = 0; ch < 4; ++ch) {
        int j = ch * 64 + lane;
        float m = motif[w * 256 + j];
        bool alive = (m != 0.f);
        unsigned long long mk = __ballot(alive);
        unsigned long long below = mk & ((1ull << lane) - 1ull);
        int pos = __popcll(below);
        if (alive) jlist[w * 256 + cnt + pos] = j;
        cnt += __popcll(mk);
      }
      if (lane == 0) {
        jcnt[w] = cnt;
        itemc[w] = cnt * ((cnt + 63) >> 6);
      }
    }
    __syncthreads();
    if (tid == 0) {
      int s = 0;
      #pragma unroll
      for (int k = 0; k < NB; ++k) { baseh[k] = s; s += itemc[k]; }
      *wqn = s;
    }
    __syncthreads();
    if (w < NB) {
      const int K = (cnt + 63) >> 6;
      const int base = baseh[w];
      int rank = 0;
      #pragma unroll
      for (int ch = 0; ch < 4; ++ch) {
        int i = ch * 64 + lane;
        bool alive = (motif[w * 256 + i] != 0.f);
        unsigned long long mk = __ballot(alive);
        unsigned long long below = mk & ((1ull << lane) - 1ull);
        int pos = __popcll(below);
        if (alive)
          for (int jt = 0; jt < K; ++jt)
            wq[base + (rank + pos) * K + jt] = (w * 256 + i) * 4 + jt;
        rank += __popcll(mk);
      }
    }
  } else {
    // ---- fill: constants for masked (bi,j) pairs
    const size_t OUT2 = (size_t)NB * NN * NN;
    int t0 = (blk - 577) * 256 + tid;       // 65536 threads, 4 pairs each
    #pragma unroll
    for (int k = 0; k < 4; ++k) {
      int p = t0 + k * 65536;               // p in [0, 262144)
      int bi = p >> 8, j = p & 255, b = bi >> 8;
      bool masked = (motif[bi] == 0.f) || (motif[b * 256 + j] == 0.f);
      if (masked) {
        out[p] = 0.5f;
        out[OUT2 + p] = 0.f;
      }
    }
  }
}

// ---------------------------------------------------------------------------
// fused: static work queue, one item per 512-THREAD block (8 waves).
// Splitting each item across 8 waves halves the per-wave phase-1/phase-2
// serial chain (we are item-latency-bound: ~5 items/CU, machine mostly idle).
// Wave (jh = w8>>2, w = w8&3): phase1 fills h-rows {q*128 + w8*16 + [0,16)},
// q in 0..1 per half; phase2 computes slots [jh*32,+32) x k2 [64w,+64)
// (acc = 2 x f32x16 = 32 AGPR/wave). W2F bf streams are duplicated between
// jh-pairs but fully L2-resident (~5 us aggregate L2 BW).
// ---------------------------------------------------------------------------
__global__ __launch_bounds__(512) void fused(const unsigned short* __restrict__ Tall,
                                             const unsigned short* __restrict__ W2F,
                                             const float* __restrict__ z,
                                             const float* __restrict__ b1,
                                             const float* __restrict__ b2,
                                             const float* __restrict__ W3,
                                             const float* __restrict__ b3,
                                             const float* __restrict__ motif,
                                             const int* __restrict__ jlist,
                                             const int* __restrict__ jcnt,
                                             const int* __restrict__ wq,
                                             const int* __restrict__ wqn,
                                             float* __restrict__ out) {
  __shared__ unsigned short h1s[64 * 264];   // [slot][h_local], stride 264
  __shared__ float red[256];

  const int bx = blockIdx.x;
  if (bx >= *wqn) return;
  const int item = wq[bx];

  const int tid = threadIdx.x;
  const int w8 = tid >> 6, lane = tid & 63;
  const int quad = lane >> 4, l16 = lane & 15;
  const int L = lane >> 5, c32 = lane & 31;
  const int w = w8 & 3, jh = w8 >> 2;
  const size_t OUT2 = (size_t)NB * NN * NN;

  const int bi = item >> 2, jt = item & 3;
  const int b = bi >> 8;
  const int cnt = jcnt[b];
  const int slotbase = jt * 64;
  const float mi_v = motif[bi];

  // phase-1 z frags gathered through jlist (each wave needs all 64 slots)
  short8 zfr[4];
  #pragma unroll
  for (int nt = 0; nt < 4; ++nt) {
    int slot = slotbase + nt * 16 + l16;
    int sc = slot < cnt ? slot : cnt - 1;
    int jj = jlist[b * 256 + sc] & 255;
    const float* zr = z + (size_t)(b * 256 + jj) * 32 + quad * 8;
    float4 a0 = *(const float4*)(zr);
    float4 a1 = *(const float4*)(zr + 4);
    zfr[nt] = pack8(a0, a1);
  }

  // epilogue constants: wave owns k2 in [64w,+64)
  float b2v[2], w3v[2];
  #pragma unroll
  for (int nt = 0; nt < 2; ++nt) {
    int k2 = w * 64 + nt * 32 + c32;
    b2v[nt] = b2[k2];
    w3v[nt] = W3[k2];
  }

  f32x16 acc[2];
  #pragma unroll
  for (int nt = 0; nt < 2; ++nt)
    acc[nt] = (f32x16){0.f,0.f,0.f,0.f,0.f,0.f,0.f,0.f,
                       0.f,0.f,0.f,0.f,0.f,0.f,0.f,0.f};

  // phase-1 T base: wave w8 covers h-rows q*128 + w8*16 + l16 (q=0,1) per half
  const unsigned short* Tbase = Tall + (size_t)bi * 16384 + (w8 * 16 + l16) * 32 + quad * 8;
  const unsigned short* Wp = W2F + w * 32768 + lane * 8;
  const float* b1base = b1 + w8 * 16 + quad * 4;

  #pragma unroll
  for (int half = 0; half < 2; ++half) {
    // ---- phase 1: wave w8 fills h-rows {q*128 + w8*16 + [0,16)} x 64 slots
    short8 tfr[2];
    #pragma unroll
    for (int q = 0; q < 2; ++q)
      tfr[q] = *(const short8*)(Tbase + half * 8192 + q * 4096);
    #pragma unroll
    for (int q = 0; q < 2; ++q) {
      float4 b1f = *(const float4*)(b1base + half * 256 + q * 128);
      f32x4 cin = {b1f.x, b1f.y, b1f.z, b1f.w};
      #pragma unroll
      for (int nt = 0; nt < 4; ++nt) {
        f32x4 d = __builtin_amdgcn_mfma_f32_16x16x32_bf16(tfr[q], zfr[nt], cin, 0, 0, 0);
        // D: row = quad*4+r -> h_rel, col = l16 -> slot within nt's 16
        uint2 p;
        p.x = cvtpk(fmaxf(d[0], 0.f), fmaxf(d[1], 0.f));
        p.y = cvtpk(fmaxf(d[2], 0.f), fmaxf(d[3], 0.f));
        *(uint2*)&h1s[(nt * 16 + l16) * 264 + q * 128 + w8 * 16 + quad * 4] = p;
      }
    }
    __syncthreads();

    // ---- phase 2: 16 u-steps (h_local = u*16 + L*8); bf 3-deep, af 2-deep
    const unsigned short* Wh = Wp + half * 16384;
    const unsigned short* h1r = &h1s[(jh * 32 + c32) * 264 + L * 8];
    short8 bfp[3][2], afp[2];
    #pragma unroll
    for (int p = 0; p < 3; ++p) {
      bfp[p][0] = *(const short8*)(Wh + p * 1024);
      bfp[p][1] = *(const short8*)(Wh + p * 1024 + 512);
    }
    afp[0] = *(const short8*)(h1r);
    afp[1] = *(const short8*)(h1r + 16);
    #pragma unroll
    for (int u = 0; u < 16; ++u) {
      const int cur = u & 1, bq = u % 3;
      short8 a0 = afp[cur];
      short8 b0 = bfp[bq][0], b1q = bfp[bq][1];
      if (u < 14)
        afp[cur] = *(const short8*)(h1r + (u + 2) * 16);
      if (u < 13) {
        bfp[bq][0] = *(const short8*)(Wh + (u + 3) * 1024);
        bfp[bq][1] = *(const short8*)(Wh + (u + 3) * 1024 + 512);
      }
      acc[0] = __builtin_amdgcn_mfma_f32_32x32x16_bf16(a0, b0, acc[0], 0, 0, 0);
      acc[1] = __builtin_amdgcn_mfma_f32_32x32x16_bf16(a0, b1q, acc[1], 0, 0, 0);
    }
    if (half == 0) __syncthreads();   // protect h1s before half-1 overwrites
  }

  // ---- epilogue: relu(h2+b2) . W3, reduce over k2 (32 lanes), 4 k-waves
  float pr[16];
  #pragma unroll
  for (int reg = 0; reg < 16; ++reg) {
    float s = 0.f;
    #pragma unroll
    for (int nt = 0; nt < 2; ++nt) {
      float v = acc[nt][reg] + b2v[nt];
      v = v > 0.f ? v : 0.f;
      s += v * w3v[nt];
    }
    s += __shfl_xor(s, 1);
    s += __shfl_xor(s, 2);
    s += __shfl_xor(s, 4);
    s += __shfl_xor(s, 8);
    s += __shfl_xor(s, 16);
    pr[reg] = s;
  }
  if (c32 == 0) {
    // slot_rel = jh*32 + (reg&3) + 8*(reg>>2) + 4*L
    #pragma unroll
    for (int g = 0; g < 4; ++g) {
      float4 vv = {pr[g * 4 + 0], pr[g * 4 + 1], pr[g * 4 + 2], pr[g * 4 + 3]};
      *(float4*)&red[w * 64 + jh * 32 + g * 8 + L * 4] = vv;
    }
  }
  __syncthreads();
  if (tid < 64) {
    int slot = slotbase + tid;
    if (slot < cnt) {
      int j = jlist[b * 256 + slot] & 255;
      float logit = red[tid] + red[64 + tid] + red[128 + tid] + red[192 + tid] + b3[0];
      float mm = mi_v * motif[b * 256 + j];
      logit *= mm;
      float map = 1.f / (1.f + expf(-logit));
      size_t idx = (size_t)bi * 256 + j;
      out[idx] = map;
      out[OUT2 + idx] = logit;
    }
  }
}

// ---------------------------------------------------------------------------
extern "C" void kernel_launch(void* const* d_in, const int* in_sizes, int n_in,
                              void* d_out, int out_size, void* d_ws, size_t ws_size,
                              hipStream_t stream) {
  const float* z     = (const float*)d_in[0];
  const float* motif = (const float*)d_in[1];
  // d_in[2] residue_mask: all-ones, unused by the reference computation
  const float* W1 = (const float*)d_in[3];
  const float* b1 = (const float*)d_in[4];
  const float* W2 = (const float*)d_in[5];
  const float* b2 = (const float*)d_in[6];
  const float* W3 = (const float*)d_in[7];
  const float* b3 = (const float*)d_in[8];
  float* out = (float*)d_out;

  char* ws = (char*)d_ws;
  unsigned short* Tall = (unsigned short*)ws;                       // 32 MiB
  unsigned short* W2F  = (unsigned short*)(ws + 33554432);          // 256 KiB
  int* jlist = (int*)(ws + 33554432 + 262144);                      // 4 KiB
  int* jcnt  = (int*)(ws + 33554432 + 262144 + 4096);               // 64 B
  int* wq    = (int*)(ws + 33554432 + 262144 + 4096 + 64);          // 16 KiB
  int* wqn   = (int*)(ws + 33554432 + 262144 + 4096 + 64 + 16384);  // 64 B

  prep<<<833, 256, 0, stream>>>(z, W1, W2, motif, W2F, Tall,
                                jlist, jcnt, wq, wqn, out);
  fused<<<4096, 512, 0, stream>>>(Tall, W2F, z, b1, b2, W3, b3, motif,
                                  jlist, jcnt, wq, wqn, out);
}

// Round 18
// 125.118 us; speedup vs baseline: 1.1272x; 1.1272x over previous
//
#include <hip/hip_runtime.h>
#include <hip/hip_bf16.h>
#include <cstdint>
#include <cstddef>

// Problem constants (B=4, N=256, D=32, H=512)
#define NB 4
#define NN 256
#define DD 32
#define HH 512

typedef __attribute__((ext_vector_type(8))) short short8;    // 8 bf16 (4 VGPRs) — MFMA A/B frag
typedef __attribute__((ext_vector_type(4))) float f32x4;     // 16x16 C/D frag
typedef __attribute__((ext_vector_type(16))) float f32x16;   // 32x32 C/D frag

// HW packed fp32->bf16 (RNE). a -> low 16, b -> high 16.
static __device__ __forceinline__ unsigned cvtpk(float a, float b) {
  unsigned r;
  asm("v_cvt_pk_bf16_f32 %0, %1, %2" : "=v"(r) : "v"(a), "v"(b));
  return r;
}
static __device__ __forceinline__ unsigned short f2bf1(float a) {
  return (unsigned short)(cvtpk(a, 0.f) & 0xffffu);
}

// build a bf16 A/B frag from 8 consecutive fp32 (two float4 loads already done)
static __device__ __forceinline__ short8 pack8(float4 a0, float4 a1) {
  union { unsigned u[4]; short8 s; } r;
  r.u[0] = cvtpk(a0.x, a0.y); r.u[1] = cvtpk(a0.z, a0.w);
  r.u[2] = cvtpk(a1.x, a1.y); r.u[3] = cvtpk(a1.z, a1.w);
  return r.s;
}

// ---------------------------------------------------------------------------
// prep (grid 577x256):
//  blk < 512 : T-GEMM block; Tall stores predicated on motif[bi]!=0.
//  blk < 576 : W2F builder.
//  blk ==576 : j-compaction + static work-queue build.
// (fill duty moved to fused's idle blocks)
// ---------------------------------------------------------------------------
__global__ __launch_bounds__(256) void prep(const float* __restrict__ z,
                                            const float* __restrict__ W1,
                                            const float* __restrict__ W2,
                                            const float* __restrict__ motif,
                                            unsigned short* __restrict__ W2F,
                                            unsigned short* __restrict__ Tall,
                                            int* __restrict__ jlist,
                                            int* __restrict__ jcnt,
                                            int* __restrict__ wq,
                                            int* __restrict__ wqn) {
  const int blk = blockIdx.x;
  const int tid = threadIdx.x;
  if (blk < 512) {
    __shared__ unsigned short w1s[16384];   // 32 KB: [w2][nt][lane][e]
    const int nblk = blk >> 4, mgrp = blk & 15;
    const int bibase = mgrp * 64;

    #pragma unroll
    for (int r = 0; r < 16; ++r) {
      int task = r * 256 + tid;
      int row = task >> 2;                  // dd = a*32 + c   (0..1023)
      int hq = task & 3;                    // which 4-float group of the 16 h
      float4 v = *(const float4*)(W1 + (size_t)row * 512 + nblk * 16 + hq * 4);
      int a = row >> 5, c = row & 31;
      int quad = a >> 3, e = a & 7;
      float hv[4] = {v.x, v.y, v.z, v.w};
      #pragma unroll
      for (int vv = 0; vv < 4; ++vv) {
        int hl = hq * 4 + vv;
        int nl = hl * 32 + c;               // n_local in [0,512)
        int w2 = nl >> 7, r7 = nl & 127;
        int l16 = r7 >> 3, nt = r7 & 7;
        w1s[((w2 * 8 + nt) * 64 + quad * 16 + l16) * 8 + e] = f2bf1(hv[vv]);
      }
    }
    __syncthreads();

    const int w2 = tid >> 6, lane = tid & 63;
    const int quad = lane >> 4, l16 = lane & 15;

    short8 bfr[8];
    #pragma unroll
    for (int nt = 0; nt < 8; ++nt)
      bfr[nt] = *(const short8*)&w1s[((w2 * 8 + nt) * 64 + lane) * 8];

    const int ncol = nblk * 512 + w2 * 128 + l16 * 8;
    #pragma unroll
    for (int mtg = 0; mtg < 2; ++mtg) {
      short8 afr[2];
      #pragma unroll
      for (int mi = 0; mi < 2; ++mi) {
        const float* zr = z + (size_t)(bibase + (mtg * 2 + mi) * 16 + l16) * 32 + quad * 8;
        float4 a0 = *(const float4*)(zr);
        float4 a1 = *(const float4*)(zr + 4);
        afr[mi] = pack8(a0, a1);
      }
      f32x4 d[2][8];
      #pragma unroll
      for (int mi = 0; mi < 2; ++mi)
        #pragma unroll
        for (int nt = 0; nt < 8; ++nt)
          d[mi][nt] = __builtin_amdgcn_mfma_f32_16x16x32_bf16(
              afr[mi], bfr[nt], (f32x4){0.f, 0.f, 0.f, 0.f}, 0, 0, 0);
      #pragma unroll
      for (int mi = 0; mi < 2; ++mi)
        #pragma unroll
        for (int r = 0; r < 4; ++r) {
          int rowbi = bibase + (mtg * 2 + mi) * 16 + quad * 4 + r;
          if (motif[rowbi] != 0.f) {        // masked rows never read by fused
            uint4 p;
            p.x = cvtpk(d[mi][0][r], d[mi][1][r]);
            p.y = cvtpk(d[mi][2][r], d[mi][3][r]);
            p.z = cvtpk(d[mi][4][r], d[mi][5][r]);
            p.w = cvtpk(d[mi][6][r], d[mi][7][r]);
            *(uint4*)&Tall[(size_t)rowbi * 16384 + ncol] = p;
          }
        }
    }
  } else if (blk < 576) {
    int f8 = (blk - 512) * 256 + tid;       // frag-slot index (8 elems each)
    int lane = f8 & 63;
    int nt = (f8 >> 6) & 1, s = (f8 >> 7) & 3, hc = (f8 >> 9) & 7, w = (f8 >> 12) & 3;
    int k2 = w * 64 + nt * 32 + (lane & 31);
    int hb = hc * 64 + s * 16 + (lane >> 5) * 8;
    float v[8];
    #pragma unroll
    for (int e = 0; e < 8; ++e) v[e] = W2[(hb + e) * 256 + k2];
    uint4 p;
    p.x = cvtpk(v[0], v[1]); p.y = cvtpk(v[2], v[3]);
    p.z = cvtpk(v[4], v[5]); p.w = cvtpk(v[6], v[7]);
    ((uint4*)W2F)[f8] = p;
  } else {
    // ---- compaction + queue build: wave w handles batch b = w
    __shared__ int itemc[4];
    __shared__ int baseh[4];
    const int w = tid >> 6, lane = tid & 63;
    int cnt = 0;
    if (w < NB) {
      #pragma unroll
      for (int ch = 0; ch < 4; ++ch) {
        int j = ch * 64 + lane;
        float m = motif[w * 256 + j];
        bool alive = (m != 0.f);
        unsigned long long mk = __ballot(alive);
        unsigned long long below = mk & ((1ull << lane) - 1ull);
        int pos = __popcll(below);
        if (alive) jlist[w * 256 + cnt + pos] = j;
        cnt += __popcll(mk);
      }
      if (lane == 0) {
        jcnt[w] = cnt;
        itemc[w] = cnt * ((cnt + 63) >> 6);
      }
    }
    __syncthreads();
    if (tid == 0) {
      int s = 0;
      #pragma unroll
      for (int k = 0; k < NB; ++k) { baseh[k] = s; s += itemc[k]; }
      *wqn = s;
    }
    __syncthreads();
    if (w < NB) {
      const int K = (cnt + 63) >> 6;
      const int base = baseh[w];
      int rank = 0;
      #pragma unroll
      for (int ch = 0; ch < 4; ++ch) {
        int i = ch * 64 + lane;
        bool alive = (motif[w * 256 + i] != 0.f);
        unsigned long long mk = __ballot(alive);
        unsigned long long below = mk & ((1ull << lane) - 1ull);
        int pos = __popcll(below);
        if (alive)
          for (int jt = 0; jt < K; ++jt)
            wq[base + (rank + pos) * K + jt] = (w * 256 + i) * 4 + jt;
        rank += __popcll(mk);
      }
    }
  }
}

// ---------------------------------------------------------------------------
// fused: static work queue, one item per 256-thread block (R16 champion body)
// + all 8 tfr fragments hoisted to item start (Tall HBM latency paid once,
// overlapped with zfr gather + phase-1 of half 0) + idle blocks (bx >= wqn)
// absorb the masked-pair fill (grid-stride, concurrent with heavy items).
// ---------------------------------------------------------------------------
__global__ __launch_bounds__(256) void fused(const unsigned short* __restrict__ Tall,
                                             const unsigned short* __restrict__ W2F,
                                             const float* __restrict__ z,
                                             const float* __restrict__ b1,
                                             const float* __restrict__ b2,
                                             const float* __restrict__ W3,
                                             const float* __restrict__ b3,
                                             const float* __restrict__ motif,
                                             const int* __restrict__ jlist,
                                             const int* __restrict__ jcnt,
                                             const int* __restrict__ wq,
                                             const int* __restrict__ wqn,
                                             float* __restrict__ out) {
  __shared__ unsigned short h1s[64 * 264];   // [slot][h_local], stride 264
  __shared__ float red[256];

  const int bx = blockIdx.x;
  const int tid = threadIdx.x;
  const size_t OUT2 = (size_t)NB * NN * NN;
  const int nq = *wqn;

  if (bx >= nq) {
    // ---- fill duty: constants for masked (bi,j) pairs, grid-stride
    const int nf = (int)gridDim.x - nq;
    for (int p = (bx - nq) * 256 + tid; p < NB * NN * NN; p += nf * 256) {
      int bi = p >> 8, j = p & 255, b = bi >> 8;
      if (motif[bi] == 0.f || motif[b * 256 + j] == 0.f) {
        out[p] = 0.5f;
        out[OUT2 + p] = 0.f;
      }
    }
    return;
  }
  const int item = wq[bx];

  const int w = tid >> 6, lane = tid & 63;
  const int quad = lane >> 4, l16 = lane & 15;
  const int L = lane >> 5, c32 = lane & 31;

  const int bi = item >> 2, jt = item & 3;
  const int b = bi >> 8;
  const int cnt = jcnt[b];
  const int slotbase = jt * 64;
  const float mi_v = motif[bi];

  // ALL tfr fragments (both halves) issued up front — one HBM round trip
  const unsigned short* Tbase = Tall + (size_t)bi * 16384 + (w * 16 + l16) * 32 + quad * 8;
  short8 tfr[8];
  #pragma unroll
  for (int q = 0; q < 8; ++q)
    tfr[q] = *(const short8*)(Tbase + q * 2048);

  // phase-1 z frags gathered through jlist
  short8 zfr[4];
  #pragma unroll
  for (int nt = 0; nt < 4; ++nt) {
    int slot = slotbase + nt * 16 + l16;
    int sc = slot < cnt ? slot : cnt - 1;
    int jj = jlist[b * 256 + sc] & 255;
    const float* zr = z + (size_t)(b * 256 + jj) * 32 + quad * 8;
    float4 a0 = *(const float4*)(zr);
    float4 a1 = *(const float4*)(zr + 4);
    zfr[nt] = pack8(a0, a1);
  }

  // epilogue constants: this wave owns k2 in [64w, 64w+64)
  float b2v[2], w3v[2];
  #pragma unroll
  for (int nt = 0; nt < 2; ++nt) {
    int k2 = w * 64 + nt * 32 + c32;
    b2v[nt] = b2[k2];
    w3v[nt] = W3[k2];
  }

  f32x16 acc[2][2];
  #pragma unroll
  for (int mt = 0; mt < 2; ++mt)
    #pragma unroll
    for (int nt = 0; nt < 2; ++nt)
      acc[mt][nt] = (f32x16){0.f,0.f,0.f,0.f,0.f,0.f,0.f,0.f,
                             0.f,0.f,0.f,0.f,0.f,0.f,0.f,0.f};

  const unsigned short* Wp = W2F + w * 32768 + lane * 8;
  const float* b1base = b1 + w * 16 + quad * 4;

  #pragma unroll
  for (int half = 0; half < 2; ++half) {
    // ---- phase 1: wave w fills h-rows {q*64 + w*16 + [0,16)} x 64 slots
    #pragma unroll
    for (int q = 0; q < 4; ++q) {
      float4 b1f = *(const float4*)(b1base + (half * 4 + q) * 64);
      f32x4 cin = {b1f.x, b1f.y, b1f.z, b1f.w};
      #pragma unroll
      for (int nt = 0; nt < 4; ++nt) {
        f32x4 d = __builtin_amdgcn_mfma_f32_16x16x32_bf16(
            tfr[half * 4 + q], zfr[nt], cin, 0, 0, 0);
        uint2 p;
        p.x = cvtpk(fmaxf(d[0], 0.f), fmaxf(d[1], 0.f));
        p.y = cvtpk(fmaxf(d[2], 0.f), fmaxf(d[3], 0.f));
        *(uint2*)&h1s[(nt * 16 + l16) * 264 + q * 64 + w * 16 + quad * 4] = p;
      }
    }
    __syncthreads();

    // ---- phase 2: 16 u-steps (h_local = u*16 + L*8); bf 3-deep, af 2-deep
    const unsigned short* Wh = Wp + half * 16384;
    const unsigned short* h1r = &h1s[c32 * 264 + L * 8];
    short8 bfp[3][2], afp[2][2];
    #pragma unroll
    for (int p = 0; p < 3; ++p) {
      bfp[p][0] = *(const short8*)(Wh + p * 1024);
      bfp[p][1] = *(const short8*)(Wh + p * 1024 + 512);
    }
    afp[0][0] = *(const short8*)(h1r);
    afp[0][1] = *(const short8*)(h1r + 32 * 264);
    afp[1][0] = *(const short8*)(h1r + 16);
    afp[1][1] = *(const short8*)(h1r + 32 * 264 + 16);
    #pragma unroll
    for (int u = 0; u < 16; ++u) {
      const int cur = u & 1, bq = u % 3;
      short8 a0 = afp[cur][0], a1 = afp[cur][1];
      short8 b0 = bfp[bq][0], b1q = bfp[bq][1];
      if (u < 14) {
        afp[cur][0] = *(const short8*)(h1r + (u + 2) * 16);
        afp[cur][1] = *(const short8*)(h1r + 32 * 264 + (u + 2) * 16);
      }
      if (u < 13) {
        bfp[bq][0] = *(const short8*)(Wh + (u + 3) * 1024);
        bfp[bq][1] = *(const short8*)(Wh + (u + 3) * 1024 + 512);
      }
      acc[0][0] = __builtin_amdgcn_mfma_f32_32x32x16_bf16(a0, b0, acc[0][0], 0, 0, 0);
      acc[0][1] = __builtin_amdgcn_mfma_f32_32x32x16_bf16(a0, b1q, acc[0][1], 0, 0, 0);
      acc[1][0] = __builtin_amdgcn_mfma_f32_32x32x16_bf16(a1, b0, acc[1][0], 0, 0, 0);
      acc[1][1] = __builtin_amdgcn_mfma_f32_32x32x16_bf16(a1, b1q, acc[1][1], 0, 0, 0);
    }
    if (half == 0) __syncthreads();   // protect h1s before half-1 overwrites
  }

  // ---- epilogue: relu(h2+b2) . W3, reduce over k2 (32 lanes), then 4 waves
  float pr[2][16];
  #pragma unroll
  for (int mt = 0; mt < 2; ++mt)
    #pragma unroll
    for (int reg = 0; reg < 16; ++reg) {
      float s = 0.f;
      #pragma unroll
      for (int nt = 0; nt < 2; ++nt) {
        float v = acc[mt][nt][reg] + b2v[nt];
        v = v > 0.f ? v : 0.f;
        s += v * w3v[nt];
      }
      s += __shfl_xor(s, 1);
      s += __shfl_xor(s, 2);
      s += __shfl_xor(s, 4);
      s += __shfl_xor(s, 8);
      s += __shfl_xor(s, 16);
      pr[mt][reg] = s;
    }
  if (c32 == 0) {
    #pragma unroll
    for (int mt = 0; mt < 2; ++mt)
      #pragma unroll
      for (int g = 0; g < 4; ++g) {
        float4 vv = {pr[mt][g * 4 + 0], pr[mt][g * 4 + 1],
                     pr[mt][g * 4 + 2], pr[mt][g * 4 + 3]};
        *(float4*)&red[w * 64 + mt * 32 + g * 8 + L * 4] = vv;
      }
  }
  __syncthreads();
  if (tid < 64) {
    int slot = slotbase + tid;
    if (slot < cnt) {
      int j = jlist[b * 256 + slot] & 255;
      float logit = red[tid] + red[64 + tid] + red[128 + tid] + red[192 + tid] + b3[0];
      float mm = mi_v * motif[b * 256 + j];
      logit *= mm;
      float map = 1.f / (1.f + expf(-logit));
      size_t idx = (size_t)bi * 256 + j;
      out[idx] = map;
      out[OUT2 + idx] = logit;
    }
  }
}

// ---------------------------------------------------------------------------
extern "C" void kernel_launch(void* const* d_in, const int* in_sizes, int n_in,
                              void* d_out, int out_size, void* d_ws, size_t ws_size,
                              hipStream_t stream) {
  const float* z     = (const float*)d_in[0];
  const float* motif = (const float*)d_in[1];
  // d_in[2] residue_mask: all-ones, unused by the reference computation
  const float* W1 = (const float*)d_in[3];
  const float* b1 = (const float*)d_in[4];
  const float* W2 = (const float*)d_in[5];
  const float* b2 = (const float*)d_in[6];
  const float* W3 = (const float*)d_in[7];
  const float* b3 = (const float*)d_in[8];
  float* out = (float*)d_out;

  char* ws = (char*)d_ws;
  unsigned short* Tall = (unsigned short*)ws;                       // 32 MiB
  unsigned short* W2F  = (unsigned short*)(ws + 33554432);          // 256 KiB
  int* jlist = (int*)(ws + 33554432 + 262144);                      // 4 KiB
  int* jcnt  = (int*)(ws + 33554432 + 262144 + 4096);               // 64 B
  int* wq    = (int*)(ws + 33554432 + 262144 + 4096 + 64);          // 16 KiB
  int* wqn   = (int*)(ws + 33554432 + 262144 + 4096 + 64 + 16384);  // 64 B

  prep<<<577, 256, 0, stream>>>(z, W1, W2, motif, W2F, Tall,
                                jlist, jcnt, wq, wqn);
  fused<<<4096, 256, 0, stream>>>(Tall, W2F, z, b1, b2, W3, b3, motif,
                                  jlist, jcnt, wq, wqn, out);
}